// Round 4
// baseline (1526.521 us; speedup 1.0000x reference)
//
#include <hip/hip_runtime.h>

#define EPSILON 0.01f

#define BLK    256     // threads per workgroup
#define SLICE  4096    // nodes per slice -> 64 KB fp32x4 LDS accumulator
#define SLOG   12      // log2(SLICE)
#define NPA    21      // chunks/slice in atomic-fallback mode

// ---------------------------------------------------------------------------
// R4: destination-sliced LDS accumulation, take 3. R2/R3's shared-counter
// queue had an unprovable intermittent race (R3: first check passed, tripwire
// re-launch diverged > tolerance) -- mechanism deleted. Each block now scans
// its edge chunk and processes matching edges inline (predicated, ~10/64
// lanes active; ~11us/pass redundant-issue cost by arithmetic). Flush is
// PLAIN coalesced stores to a per-(slice,chunk) staging tile; node-grid
// reduce kernels sum the P partials (R1 showed plain stores run at full BW
// -- the ~20G trans/s memory-side atomic wall is what we're removing).
// Staged mode has ZERO global atomics. ws too small -> R0-proven
// coalesced-atomic flush fallback.
// ---------------------------------------------------------------------------

template<int PASS, int STAGED>
__global__ void __launch_bounds__(BLK) edge_slice_kernel(
    const float4* __restrict__ boo,   // [E*4] rows of B
    const int*    __restrict__ row,
    const int*    __restrict__ col,
    const float4* __restrict__ src,   // PASS1: x[N]   PASS2: v[N]
    const float*  __restrict__ mask,  // fallback PASS2 flush scale
    float*        __restrict__ dst,   // STAGED: stage base; else ATx/out
    int N, long long E, int P)
{
    __shared__ float acc[SLICE * 4];  // 64 KB

    const int s    = blockIdx.x / P;
    const int p    = blockIdx.x - s * P;
    const int base = s << SLOG;
    const int lim  = min(SLICE, N - base);

    for (int i = threadIdx.x; i < SLICE * 4; i += BLK) acc[i] = 0.0f;
    __syncthreads();

    long long chunk = (((E + P - 1) / P) + 3) & ~3LL;   // multiple of 4
    long long start = (long long)p * chunk;
    long long end   = start + chunk; if (end > E) end = E;

    const int* __restrict__ key = (PASS == 1) ? col : row;

    auto body = [&](long long e, int kk) {
        const float4* B = boo + e * 4;
        float4 b0 = B[0], b1 = B[1], b2 = B[2], b3 = B[3];
        float* a = acc + (kk - base) * 4;
        if (PASS == 1) {
            float4 xv = src[row[e]];
            // msg_t[i] = sum_j B[j][i] * x[j]
            atomicAdd(a + 0, b0.x*xv.x + b1.x*xv.y + b2.x*xv.z + b3.x*xv.w);
            atomicAdd(a + 1, b0.y*xv.x + b1.y*xv.y + b2.y*xv.z + b3.y*xv.w);
            atomicAdd(a + 2, b0.z*xv.x + b1.z*xv.y + b2.z*xv.z + b3.z*xv.w);
            atomicAdd(a + 3, b0.w*xv.x + b1.w*xv.y + b2.w*xv.z + b3.w*xv.w);
        } else {
            float4 v = src[col[e]];
            // msg[i] = dot(B[i][:], v)
            atomicAdd(a + 0, b0.x*v.x + b0.y*v.y + b0.z*v.z + b0.w*v.w);
            atomicAdd(a + 1, b1.x*v.x + b1.y*v.y + b1.z*v.z + b1.w*v.w);
            atomicAdd(a + 2, b2.x*v.x + b2.y*v.y + b2.z*v.z + b2.w*v.w);
            atomicAdd(a + 3, b3.x*v.x + b3.y*v.y + b3.z*v.z + b3.w*v.w);
        }
    };

    for (long long t0 = start + (long long)threadIdx.x * 4; t0 < end;
         t0 += (long long)BLK * 4) {
        if (t0 + 4 <= end) {
            int4 k = *reinterpret_cast<const int4*>(key + t0);
            if ((unsigned)(k.x - base) < (unsigned)lim) body(t0 + 0, k.x);
            if ((unsigned)(k.y - base) < (unsigned)lim) body(t0 + 1, k.y);
            if ((unsigned)(k.z - base) < (unsigned)lim) body(t0 + 2, k.z);
            if ((unsigned)(k.w - base) < (unsigned)lim) body(t0 + 3, k.w);
        } else {
            for (long long e = t0; e < end; ++e) {     // generic tail guard
                int kk = key[e];
                if ((unsigned)(kk - base) < (unsigned)lim) body(e, kk);
            }
        }
    }
    __syncthreads();

    if (STAGED) {
        // plain coalesced stores to this block's private staging tile
        float* st = dst + ((long long)s * P + p) * (SLICE * 4);
        for (int f = threadIdx.x; f < lim * 4; f += BLK) st[f] = acc[f];
    } else if (PASS == 1) {
        for (int f = threadIdx.x; f < lim * 4; f += BLK)
            unsafeAtomicAdd(dst + ((long long)base * 4 + f), acc[f]);
    } else {
        for (int f = threadIdx.x; f < lim * 4; f += BLK) {
            float mv = mask[base + (f >> 2)];
            unsafeAtomicAdd(dst + ((long long)base * 4 + f), acc[f] * mv);
        }
    }
}

// Staged mid: v = (sum_p stage1[s][p]) * diag * mask
__global__ void __launch_bounds__(BLK) mid_staged_kernel(
    const float4* __restrict__ stage,  // [S*P][SLICE] float4 tiles
    const float4* __restrict__ d4,
    const float*  __restrict__ mask,
    float4* __restrict__ v4,
    int N, int P)
{
    int n = blockIdx.x * BLK + threadIdx.x;
    if (n >= N) return;
    int s = n >> SLOG, local = n & (SLICE - 1);
    const float4* t = stage + (long long)s * P * SLICE + local;
    float4 a = make_float4(0.f, 0.f, 0.f, 0.f);
    for (int p = 0; p < P; ++p) {
        float4 u = t[(long long)p * SLICE];
        a.x += u.x; a.y += u.y; a.z += u.z; a.w += u.w;
    }
    float4 dv = d4[n];
    float  m  = mask[n];
    a.x *= dv.x * m; a.y *= dv.y * m; a.z *= dv.z * m; a.w *= dv.w * m;
    v4[n] = a;
}

// Staged final: out = EPSILON*x*diag + mask * (sum_p stage2[s][p])
__global__ void __launch_bounds__(BLK) fin_staged_kernel(
    const float4* __restrict__ stage,
    const float4* __restrict__ x4,
    const float4* __restrict__ d4,
    const float*  __restrict__ mask,
    float4* __restrict__ out4,
    int N, int P)
{
    int n = blockIdx.x * BLK + threadIdx.x;
    if (n >= N) return;
    int s = n >> SLOG, local = n & (SLICE - 1);
    const float4* t = stage + (long long)s * P * SLICE + local;
    float4 a = make_float4(0.f, 0.f, 0.f, 0.f);
    for (int p = 0; p < P; ++p) {
        float4 u = t[(long long)p * SLICE];
        a.x += u.x; a.y += u.y; a.z += u.z; a.w += u.w;
    }
    float4 xv = x4[n];
    float4 dv = d4[n];
    float  m  = mask[n];
    float4 o;
    o.x = EPSILON * xv.x * dv.x + a.x * m;
    o.y = EPSILON * xv.y * dv.y + a.y * m;
    o.z = EPSILON * xv.z * dv.z + a.z * m;
    o.w = EPSILON * xv.w * dv.w + a.w * m;
    out4[n] = o;
}

// Fallback mid: v = ATx * diag * mask (in place); out = EPSILON * x * diag
__global__ void __launch_bounds__(BLK) mid_atomic_kernel(
    const float4* __restrict__ x4,
    const float4* __restrict__ d4,
    const float*  __restrict__ mask,
    float4* __restrict__ atx,
    float4* __restrict__ out4,
    int N)
{
    int n = blockIdx.x * BLK + threadIdx.x;
    if (n >= N) return;
    float4 a  = atx[n];
    float4 dv = d4[n];
    float  m  = mask[n];
    a.x *= dv.x * m; a.y *= dv.y * m; a.z *= dv.z * m; a.w *= dv.w * m;
    atx[n] = a;
    float4 xv = x4[n];
    float4 o;
    o.x = EPSILON * xv.x * dv.x; o.y = EPSILON * xv.y * dv.y;
    o.z = EPSILON * xv.z * dv.z; o.w = EPSILON * xv.w * dv.w;
    out4[n] = o;
}

extern "C" void kernel_launch(void* const* d_in, const int* in_sizes, int n_in,
                              void* d_out, int out_size, void* d_ws, size_t ws_size,
                              hipStream_t stream) {
    const float* x    = (const float*)d_in[0];
    const int*   ei   = (const int*)d_in[1];
    const float* boo  = (const float*)d_in[2];
    const float* mask = (const float*)d_in[3];
    const float* diag = (const float*)d_in[4];
    float* out = (float*)d_out;

    int N = in_sizes[0] / 4;
    long long E = in_sizes[1] / 2;
    const int* row = ei;
    const int* col = ei + E;

    int S = (N + SLICE - 1) / SLICE;
    size_t vbytes = (size_t)N * 4 * sizeof(float);
    size_t tileb  = (size_t)SLICE * 4 * sizeof(float);   // 64 KB

    int P = 0;                                           // staged chunks/slice
    for (int cand = 16; cand >= 2; cand >>= 1)
        if (ws_size >= vbytes + (size_t)S * cand * tileb) { P = cand; break; }

    float* v = (float*)d_ws;                             // [N*4] scaled ATx
    const int gNode = (N + BLK - 1) / BLK;

    if (P > 0) {
        float* stage = v + (size_t)N * 4;                // S*P tiles
        int gEdge = S * P;
        edge_slice_kernel<1, 1><<<gEdge, BLK, 0, stream>>>(
            (const float4*)boo, row, col, (const float4*)x, mask, stage, N, E, P);
        mid_staged_kernel<<<gNode, BLK, 0, stream>>>(
            (const float4*)stage, (const float4*)diag, mask, (float4*)v, N, P);
        edge_slice_kernel<2, 1><<<gEdge, BLK, 0, stream>>>(
            (const float4*)boo, row, col, (const float4*)v, mask, stage, N, E, P);
        fin_staged_kernel<<<gNode, BLK, 0, stream>>>(
            (const float4*)stage, (const float4*)x, (const float4*)diag, mask,
            (float4*)out, N, P);
    } else {
        // R0-proven coalesced-atomic flush path (needs only N*16 B of ws)
        hipMemsetAsync(v, 0, vbytes, stream);
        int gEdge = S * NPA;
        edge_slice_kernel<1, 0><<<gEdge, BLK, 0, stream>>>(
            (const float4*)boo, row, col, (const float4*)x, mask, v, N, E, NPA);
        mid_atomic_kernel<<<gNode, BLK, 0, stream>>>(
            (const float4*)x, (const float4*)diag, mask,
            (float4*)v, (float4*)out, N);
        edge_slice_kernel<2, 0><<<gEdge, BLK, 0, stream>>>(
            (const float4*)boo, row, col, (const float4*)v, mask, out, N, E, NPA);
    }
}

// Round 5
// 544.375 us; speedup vs baseline: 2.8042x; 2.8042x over previous
//
#include <hip/hip_runtime.h>

#define EPSILON 0.01f

#define BLK    256     // threads per workgroup
#define SLICE  2048    // nodes per slice -> 32 KB fp32x4 LDS accumulator
#define SLOG   11      // log2(SLICE)
#define PCH    26      // edge-pass chunks per slice (grid ~ 49*26=1274, ~5/CU)
#define BCH    2048    // edges per binning block
#define MAXS   64      // max slices supported by LDS histograms

// ---------------------------------------------------------------------------
// R5: bin-then-dense. R4 proved LDS-slice accumulation + staged flush correct
// and atomic-free, but its predicated 25-sweep scan was pure issue waste
// (VALU 6.8%, HBM 2.9%, occ 18%). Fix: one binning pass materializes, for
// each destination slice, the compacted edge list (8B records {e, loc|src})
// for BOTH passes; edge passes then run dense (every lane a real edge, one
// sweep), 32KB LDS (5 blocks/CU) for latency hiding. Race surface: one
// commutative global atomicAdd per (block,slice) range reservation.
// ---------------------------------------------------------------------------

__global__ void init_cursors(int* cur1, int* cur2, int S, int cap) {
    int t = threadIdx.x;
    if (t < S) { cur1[t] = t * cap; cur2[t] = t * cap; }
}

__global__ void __launch_bounds__(BLK) bin_kernel(
    const int* __restrict__ row, const int* __restrict__ col,
    int2* __restrict__ bins1, int2* __restrict__ bins2,
    int* __restrict__ cur1, int* __restrict__ cur2,
    long long E, int S)
{
    __shared__ int h1[MAXS], h2[MAXS], b1[MAXS], b2[MAXS];
    const int t = threadIdx.x;
    if (t < S) { h1[t] = 0; h2[t] = 0; }
    __syncthreads();

    long long start = (long long)blockIdx.x * BCH;
    long long end   = start + BCH; if (end > E) end = E;

    // count both keys
    for (long long t0 = start + (long long)t * 4; t0 < end; t0 += (long long)BLK * 4) {
        if (t0 + 4 <= end) {
            int4 c = *reinterpret_cast<const int4*>(col + t0);
            int4 r = *reinterpret_cast<const int4*>(row + t0);
            atomicAdd(&h1[c.x >> SLOG], 1); atomicAdd(&h1[c.y >> SLOG], 1);
            atomicAdd(&h1[c.z >> SLOG], 1); atomicAdd(&h1[c.w >> SLOG], 1);
            atomicAdd(&h2[r.x >> SLOG], 1); atomicAdd(&h2[r.y >> SLOG], 1);
            atomicAdd(&h2[r.z >> SLOG], 1); atomicAdd(&h2[r.w >> SLOG], 1);
        } else {
            for (long long e = t0; e < end; ++e) {
                atomicAdd(&h1[col[e] >> SLOG], 1);
                atomicAdd(&h2[row[e] >> SLOG], 1);
            }
        }
    }
    __syncthreads();
    if (t < S) {
        b1[t] = atomicAdd(&cur1[t], h1[t]); h1[t] = 0;
        b2[t] = atomicAdd(&cur2[t], h2[t]); h2[t] = 0;
    }
    __syncthreads();

    // scatter records: bins1 keyed by col (rec: e, col_local<<17 | row)
    //                  bins2 keyed by row (rec: e, row_local<<17 | col)
    for (long long t0 = start + (long long)t * 4; t0 < end; t0 += (long long)BLK * 4) {
        long long lim4 = (t0 + 4 <= end) ? t0 + 4 : end;
        if (t0 + 4 <= end) {
            int4 c = *reinterpret_cast<const int4*>(col + t0);
            int4 r = *reinterpret_cast<const int4*>(row + t0);
            int cc[4] = {c.x, c.y, c.z, c.w};
            int rr[4] = {r.x, r.y, r.z, r.w};
            #pragma unroll
            for (int u = 0; u < 4; ++u) {
                int s1 = cc[u] >> SLOG;
                int i1 = b1[s1] + atomicAdd(&h1[s1], 1);
                bins1[i1] = make_int2((int)(t0 + u), ((cc[u] & (SLICE - 1)) << 17) | rr[u]);
                int s2 = rr[u] >> SLOG;
                int i2 = b2[s2] + atomicAdd(&h2[s2], 1);
                bins2[i2] = make_int2((int)(t0 + u), ((rr[u] & (SLICE - 1)) << 17) | cc[u]);
            }
        } else {
            for (long long e = t0; e < lim4; ++e) {
                int cv = col[e], rv = row[e];
                int s1 = cv >> SLOG;
                int i1 = b1[s1] + atomicAdd(&h1[s1], 1);
                bins1[i1] = make_int2((int)e, ((cv & (SLICE - 1)) << 17) | rv);
                int s2 = rv >> SLOG;
                int i2 = b2[s2] + atomicAdd(&h2[s2], 1);
                bins2[i2] = make_int2((int)e, ((rv & (SLICE - 1)) << 17) | cv);
            }
        }
    }
}

// Dense sliced edge pass. PASS1: msg_t[i]=sum_j B[j][i]*x[src]; PASS2:
// msg[i]=dot(B[i][:],v[src]). STAGED: plain stores to private tile; else
// coalesced global atomics (PASS2 applies mask at flush).
template<int PASS, int STAGED>
__global__ void __launch_bounds__(BLK) pass_kernel(
    const float4* __restrict__ boo,
    const int2*   __restrict__ bins,
    const int*    __restrict__ cur,    // post-sort cursors (start + count)
    const float4* __restrict__ src,
    const float*  __restrict__ mask,
    float*        __restrict__ dst,    // STAGED: stage base; else ATx/out
    int N, int cap, int P)
{
    __shared__ float acc[SLICE * 4];   // 32 KB

    const int s    = blockIdx.x / P;
    const int p    = blockIdx.x - s * P;
    const int base = s << SLOG;
    const int lim  = min(SLICE, N - base);

    for (int i = threadIdx.x; i < SLICE * 4; i += BLK) acc[i] = 0.0f;
    __syncthreads();

    const int cnt = cur[s] - s * cap;
    const int lo  = (int)((long long)cnt * p / P);
    const int hi  = (int)((long long)cnt * (p + 1) / P);
    const int2* __restrict__ bin = bins + (size_t)s * cap;

    for (int i = lo + (int)threadIdx.x; i < hi; i += BLK) {
        int2 rec = bin[i];
        const float4* B = boo + (long long)rec.x * 4;
        float4 b0 = B[0], b1 = B[1], b2 = B[2], b3 = B[3];
        float4 v = src[rec.y & 0x1FFFF];
        float* a = acc + (((unsigned)rec.y) >> 17) * 4;
        if (PASS == 1) {
            atomicAdd(a + 0, b0.x*v.x + b1.x*v.y + b2.x*v.z + b3.x*v.w);
            atomicAdd(a + 1, b0.y*v.x + b1.y*v.y + b2.y*v.z + b3.y*v.w);
            atomicAdd(a + 2, b0.z*v.x + b1.z*v.y + b2.z*v.z + b3.z*v.w);
            atomicAdd(a + 3, b0.w*v.x + b1.w*v.y + b2.w*v.z + b3.w*v.w);
        } else {
            atomicAdd(a + 0, b0.x*v.x + b0.y*v.y + b0.z*v.z + b0.w*v.w);
            atomicAdd(a + 1, b1.x*v.x + b1.y*v.y + b1.z*v.z + b1.w*v.w);
            atomicAdd(a + 2, b2.x*v.x + b2.y*v.y + b2.z*v.z + b2.w*v.w);
            atomicAdd(a + 3, b3.x*v.x + b3.y*v.y + b3.z*v.z + b3.w*v.w);
        }
    }
    __syncthreads();

    if (STAGED) {
        float* st = dst + (size_t)blockIdx.x * (SLICE * 4);
        for (int f = threadIdx.x; f < lim * 4; f += BLK) st[f] = acc[f];
    } else if (PASS == 1) {
        for (int f = threadIdx.x; f < lim * 4; f += BLK)
            unsafeAtomicAdd(dst + ((long long)base * 4 + f), acc[f]);
    } else {
        for (int f = threadIdx.x; f < lim * 4; f += BLK) {
            float mv = mask[base + (f >> 2)];
            unsafeAtomicAdd(dst + ((long long)base * 4 + f), acc[f] * mv);
        }
    }
}

// Staged mid: v = (sum_p stage1[s*P+p]) * diag * mask
__global__ void __launch_bounds__(BLK) mid_staged_kernel(
    const float4* __restrict__ stage,
    const float4* __restrict__ d4,
    const float*  __restrict__ mask,
    float4* __restrict__ v4,
    int N, int P)
{
    int n = blockIdx.x * BLK + threadIdx.x;
    if (n >= N) return;
    int s = n >> SLOG, local = n & (SLICE - 1);
    const float4* t = stage + ((size_t)s * P) * SLICE + local;
    float4 a = make_float4(0.f, 0.f, 0.f, 0.f);
    for (int p = 0; p < P; ++p) {
        float4 u = t[(size_t)p * SLICE];
        a.x += u.x; a.y += u.y; a.z += u.z; a.w += u.w;
    }
    float4 dv = d4[n];
    float  m  = mask[n];
    a.x *= dv.x * m; a.y *= dv.y * m; a.z *= dv.z * m; a.w *= dv.w * m;
    v4[n] = a;
}

// Staged final: out = EPSILON*x*diag + mask * (sum_p stage2[s*P+p])
__global__ void __launch_bounds__(BLK) fin_staged_kernel(
    const float4* __restrict__ stage,
    const float4* __restrict__ x4,
    const float4* __restrict__ d4,
    const float*  __restrict__ mask,
    float4* __restrict__ out4,
    int N, int P)
{
    int n = blockIdx.x * BLK + threadIdx.x;
    if (n >= N) return;
    int s = n >> SLOG, local = n & (SLICE - 1);
    const float4* t = stage + ((size_t)s * P) * SLICE + local;
    float4 a = make_float4(0.f, 0.f, 0.f, 0.f);
    for (int p = 0; p < P; ++p) {
        float4 u = t[(size_t)p * SLICE];
        a.x += u.x; a.y += u.y; a.z += u.z; a.w += u.w;
    }
    float4 xv = x4[n];
    float4 dv = d4[n];
    float  m  = mask[n];
    float4 o;
    o.x = EPSILON * xv.x * dv.x + a.x * m;
    o.y = EPSILON * xv.y * dv.y + a.y * m;
    o.z = EPSILON * xv.z * dv.z + a.z * m;
    o.w = EPSILON * xv.w * dv.w + a.w * m;
    out4[n] = o;
}

// Tier-2 mid: v = v * diag * mask (in place); out = EPSILON * x * diag
__global__ void __launch_bounds__(BLK) mid_atomic_kernel(
    const float4* __restrict__ x4,
    const float4* __restrict__ d4,
    const float*  __restrict__ mask,
    float4* __restrict__ atx,
    float4* __restrict__ out4,
    int N)
{
    int n = blockIdx.x * BLK + threadIdx.x;
    if (n >= N) return;
    float4 a  = atx[n];
    float4 dv = d4[n];
    float  m  = mask[n];
    a.x *= dv.x * m; a.y *= dv.y * m; a.z *= dv.z * m; a.w *= dv.w * m;
    atx[n] = a;
    float4 xv = x4[n];
    float4 o;
    o.x = EPSILON * xv.x * dv.x; o.y = EPSILON * xv.y * dv.y;
    o.z = EPSILON * xv.z * dv.z; o.w = EPSILON * xv.w * dv.w;
    out4[n] = o;
}

// ---- Tier-3 fallback: R0 kernels verbatim (proven 544us) -----------------
__global__ void __launch_bounds__(256) spmvt_kernel(
    const float4* __restrict__ boo, const int* __restrict__ row,
    const int* __restrict__ col, const float* __restrict__ x,
    float* __restrict__ ATx, long long E)
{
    long long t = (long long)blockIdx.x * blockDim.x + threadIdx.x;
    long long e = t >> 2;
    int j = (int)(t & 3);
    if (e >= E) return;
    float4 b = boo[e * 4 + j];
    int r = row[e];
    float xj = x[r * 4 + j];
    float4 p;
    p.x = b.x * xj; p.y = b.y * xj; p.z = b.z * xj; p.w = b.w * xj;
    p.x += __shfl_xor(p.x, 1); p.y += __shfl_xor(p.y, 1);
    p.z += __shfl_xor(p.z, 1); p.w += __shfl_xor(p.w, 1);
    p.x += __shfl_xor(p.x, 2); p.y += __shfl_xor(p.y, 2);
    p.z += __shfl_xor(p.z, 2); p.w += __shfl_xor(p.w, 2);
    float v = (j == 0) ? p.x : (j == 1) ? p.y : (j == 2) ? p.z : p.w;
    int c = col[e];
    unsafeAtomicAdd(&ATx[c * 4 + j], v);
}

__global__ void __launch_bounds__(256) spmv_kernel(
    const float4* __restrict__ boo, const int* __restrict__ row,
    const int* __restrict__ col, const float* __restrict__ vv,
    const float* __restrict__ mask, float* __restrict__ out, long long E)
{
    long long t = (long long)blockIdx.x * blockDim.x + threadIdx.x;
    long long e = t >> 2;
    int i = (int)(t & 3);
    if (e >= E) return;
    float4 b = boo[e * 4 + i];
    int c = col[e];
    const float4* v4 = (const float4*)vv;
    float4 v = v4[c];
    float mi = b.x * v.x + b.y * v.y + b.z * v.z + b.w * v.w;
    int r = row[e];
    float mr = mask[r];
    unsafeAtomicAdd(&out[r * 4 + i], mi * mr);
}

extern "C" void kernel_launch(void* const* d_in, const int* in_sizes, int n_in,
                              void* d_out, int out_size, void* d_ws, size_t ws_size,
                              hipStream_t stream) {
    const float* x    = (const float*)d_in[0];
    const int*   ei   = (const int*)d_in[1];
    const float* boo  = (const float*)d_in[2];
    const float* mask = (const float*)d_in[3];
    const float* diag = (const float*)d_in[4];
    float* out = (float*)d_out;

    int N = in_sizes[0] / 4;
    long long E = in_sizes[1] / 2;
    const int* row = ei;
    const int* col = ei + E;

    int S = (N + SLICE - 1) >> SLOG;
    int cap = (int)((E + S - 1) / S);
    cap += cap * 3 / 10;                     // 30% slack (keys fixed; 60+ sigma)
    cap = (cap + 255) & ~255;

    size_t o_v   = 0;
    size_t o_cur = ((size_t)N * 16 + 255) & ~(size_t)255;
    size_t o_b1  = o_cur + 1024;
    size_t szb   = (size_t)S * cap * 8;
    size_t o_b2  = o_b1 + szb;
    size_t o_st  = o_b2 + szb;
    size_t szst  = (size_t)S * PCH * SLICE * 16;

    bool ok   = (S <= MAXS) && (N <= (1 << 17)) && ((E & 3) == 0 || true);
    int  tier = (!ok) ? 3 : (ws_size >= o_st + szst) ? 1
                          : (ws_size >= o_st)        ? 2 : 3;

    float* v     = (float*)((char*)d_ws + o_v);
    int*   cur1  = (int*)((char*)d_ws + o_cur);
    int*   cur2  = cur1 + 128;
    int2*  bins1 = (int2*)((char*)d_ws + o_b1);
    int2*  bins2 = (int2*)((char*)d_ws + o_b2);
    float* stage = (float*)((char*)d_ws + o_st);

    const int gNode = (N + BLK - 1) / BLK;
    const int gBin  = (int)((E + BCH - 1) / BCH);
    const int gPass = S * PCH;

    if (tier <= 2) {
        init_cursors<<<1, MAXS, 0, stream>>>(cur1, cur2, S, cap);
        bin_kernel<<<gBin, BLK, 0, stream>>>(row, col, bins1, bins2, cur1, cur2, E, S);
        if (tier == 1) {
            pass_kernel<1, 1><<<gPass, BLK, 0, stream>>>(
                (const float4*)boo, bins1, cur1, (const float4*)x, mask, stage, N, cap, PCH);
            mid_staged_kernel<<<gNode, BLK, 0, stream>>>(
                (const float4*)stage, (const float4*)diag, mask, (float4*)v, N, PCH);
            pass_kernel<2, 1><<<gPass, BLK, 0, stream>>>(
                (const float4*)boo, bins2, cur2, (const float4*)v, mask, stage, N, cap, PCH);
            fin_staged_kernel<<<gNode, BLK, 0, stream>>>(
                (const float4*)stage, (const float4*)x, (const float4*)diag, mask,
                (float4*)out, N, PCH);
        } else {
            hipMemsetAsync(v, 0, (size_t)N * 16, stream);
            pass_kernel<1, 0><<<gPass, BLK, 0, stream>>>(
                (const float4*)boo, bins1, cur1, (const float4*)x, mask, v, N, cap, PCH);
            mid_atomic_kernel<<<gNode, BLK, 0, stream>>>(
                (const float4*)x, (const float4*)diag, mask, (float4*)v, (float4*)out, N);
            pass_kernel<2, 0><<<gPass, BLK, 0, stream>>>(
                (const float4*)boo, bins2, cur2, (const float4*)v, mask, out, N, cap, PCH);
        }
    } else {
        // Tier 3: R0-proven path
        hipMemsetAsync(v, 0, (size_t)N * 16, stream);
        long long T = E * 4;
        int gEdge = (int)((T + BLK - 1) / BLK);
        spmvt_kernel<<<gEdge, BLK, 0, stream>>>(
            (const float4*)boo, row, col, x, v, E);
        mid_atomic_kernel<<<gNode, BLK, 0, stream>>>(
            (const float4*)x, (const float4*)diag, mask, (float4*)v, (float4*)out, N);
        spmv_kernel<<<gEdge, BLK, 0, stream>>>(
            (const float4*)boo, row, col, v, mask, out, E);
    }
}

// Round 6
// 524.510 us; speedup vs baseline: 2.9104x; 1.0379x over previous
//
#include <hip/hip_runtime.h>

#define EPSILON 0.01f

#define BLK    256     // threads per workgroup
#define NW     4       // waves per workgroup
#define SLICE  2048    // nodes per slice -> 32 KB fp32x4 LDS accumulator
#define SLOG   11      // log2(SLICE)
#define PCH    26      // edge-pass chunks per slice (grid ~ 49*26=1274, ~5/CU)
#define BCH    4096    // edges per binning block (halves global cursor atomics)
#define MAXS   64      // max slices supported by LDS histograms
#define HP     65      // padded histogram stride (bank-spread)

// ---------------------------------------------------------------------------
// R6: R5's bin-then-dense passed at 544us; pass_kernel is latency-bound
// (2.25 TB/s, VALU 2.9%, 5 waves/SIMD x ~1 gather-chain in flight ~= 2.3 TB/s
// by arithmetic). Fix 1: 2-way unroll -> 2x memory-level parallelism.
// bin_kernel serializes on block-shared LDS histogram atomics (256 threads x
// 8 adds into 49 words) + ~150K same-address global cursor atomics. Fix 2:
// per-wave histograms/cursors (padded stride 65) + BCH 2048->4096.
// Structure, tiers, and flush (atomic-free staging) unchanged from R5.
// ---------------------------------------------------------------------------

__global__ void init_cursors(int* cur1, int* cur2, int S, int cap) {
    int t = threadIdx.x;
    if (t < S) { cur1[t] = t * cap; cur2[t] = t * cap; }
}

__global__ void __launch_bounds__(BLK) bin_kernel(
    const int* __restrict__ row, const int* __restrict__ col,
    int2* __restrict__ bins1, int2* __restrict__ bins2,
    int* __restrict__ cur1, int* __restrict__ cur2,
    long long E, int S)
{
    __shared__ int h1[NW * HP], h2[NW * HP];   // per-wave hist / rank counters
    __shared__ int bw1[NW * HP], bw2[NW * HP]; // per-wave base cursors
    const int t = threadIdx.x;
    const int w = t >> 6;

    for (int i = t; i < NW * HP; i += BLK) { h1[i] = 0; h2[i] = 0; }
    __syncthreads();

    long long start = (long long)blockIdx.x * BCH;
    long long end   = start + BCH; if (end > E) end = E;

    // count both keys (per-wave histograms: no cross-wave contention)
    for (long long t0 = start + (long long)t * 4; t0 < end; t0 += (long long)BLK * 4) {
        if (t0 + 4 <= end) {
            int4 c = *reinterpret_cast<const int4*>(col + t0);
            int4 r = *reinterpret_cast<const int4*>(row + t0);
            atomicAdd(&h1[w * HP + (c.x >> SLOG)], 1);
            atomicAdd(&h1[w * HP + (c.y >> SLOG)], 1);
            atomicAdd(&h1[w * HP + (c.z >> SLOG)], 1);
            atomicAdd(&h1[w * HP + (c.w >> SLOG)], 1);
            atomicAdd(&h2[w * HP + (r.x >> SLOG)], 1);
            atomicAdd(&h2[w * HP + (r.y >> SLOG)], 1);
            atomicAdd(&h2[w * HP + (r.z >> SLOG)], 1);
            atomicAdd(&h2[w * HP + (r.w >> SLOG)], 1);
        } else {
            for (long long e = t0; e < end; ++e) {
                atomicAdd(&h1[w * HP + (col[e] >> SLOG)], 1);
                atomicAdd(&h2[w * HP + (row[e] >> SLOG)], 1);
            }
        }
    }
    __syncthreads();

    // one global cursor atomic per (block, slice); per-wave prefix bases
    if (t < S) {
        int a0 = h1[0 * HP + t], a1 = h1[1 * HP + t],
            a2 = h1[2 * HP + t], a3 = h1[3 * HP + t];
        int g = atomicAdd(&cur1[t], a0 + a1 + a2 + a3);
        bw1[0 * HP + t] = g;
        bw1[1 * HP + t] = g + a0;
        bw1[2 * HP + t] = g + a0 + a1;
        bw1[3 * HP + t] = g + a0 + a1 + a2;
        int c0 = h2[0 * HP + t], c1 = h2[1 * HP + t],
            c2 = h2[2 * HP + t], c3 = h2[3 * HP + t];
        int g2 = atomicAdd(&cur2[t], c0 + c1 + c2 + c3);
        bw2[0 * HP + t] = g2;
        bw2[1 * HP + t] = g2 + c0;
        bw2[2 * HP + t] = g2 + c0 + c1;
        bw2[3 * HP + t] = g2 + c0 + c1 + c2;
    }
    __syncthreads();
    for (int i = t; i < NW * HP; i += BLK) { h1[i] = 0; h2[i] = 0; }
    __syncthreads();

    // scatter records: bins1 keyed by col (rec: e, col_local<<17 | row)
    //                  bins2 keyed by row (rec: e, row_local<<17 | col)
    for (long long t0 = start + (long long)t * 4; t0 < end; t0 += (long long)BLK * 4) {
        if (t0 + 4 <= end) {
            int4 c = *reinterpret_cast<const int4*>(col + t0);
            int4 r = *reinterpret_cast<const int4*>(row + t0);
            int cc[4] = {c.x, c.y, c.z, c.w};
            int rr[4] = {r.x, r.y, r.z, r.w};
            #pragma unroll
            for (int u = 0; u < 4; ++u) {
                int s1 = cc[u] >> SLOG;
                int i1 = bw1[w * HP + s1] + atomicAdd(&h1[w * HP + s1], 1);
                bins1[i1] = make_int2((int)(t0 + u), ((cc[u] & (SLICE - 1)) << 17) | rr[u]);
                int s2 = rr[u] >> SLOG;
                int i2 = bw2[w * HP + s2] + atomicAdd(&h2[w * HP + s2], 1);
                bins2[i2] = make_int2((int)(t0 + u), ((rr[u] & (SLICE - 1)) << 17) | cc[u]);
            }
        } else {
            for (long long e = t0; e < end; ++e) {
                int cv = col[e], rv = row[e];
                int s1 = cv >> SLOG;
                int i1 = bw1[w * HP + s1] + atomicAdd(&h1[w * HP + s1], 1);
                bins1[i1] = make_int2((int)e, ((cv & (SLICE - 1)) << 17) | rv);
                int s2 = rv >> SLOG;
                int i2 = bw2[w * HP + s2] + atomicAdd(&h2[w * HP + s2], 1);
                bins2[i2] = make_int2((int)e, ((rv & (SLICE - 1)) << 17) | cv);
            }
        }
    }
}

// Dense sliced edge pass, 2-way unrolled for MLP. PASS1: msg_t[i]=sum_j
// B[j][i]*x[src]; PASS2: msg[i]=dot(B[i][:],v[src]).
template<int PASS, int STAGED>
__global__ void __launch_bounds__(BLK) pass_kernel(
    const float4* __restrict__ boo,
    const int2*   __restrict__ bins,
    const int*    __restrict__ cur,    // post-bin cursors (start + count)
    const float4* __restrict__ src,
    const float*  __restrict__ mask,
    float*        __restrict__ dst,    // STAGED: stage base; else ATx/out
    int N, int cap, int P)
{
    __shared__ float acc[SLICE * 4];   // 32 KB

    const int s    = blockIdx.x / P;
    const int p    = blockIdx.x - s * P;
    const int base = s << SLOG;
    const int lim  = min(SLICE, N - base);

    for (int i = threadIdx.x; i < SLICE * 4; i += BLK) acc[i] = 0.0f;
    __syncthreads();

    const int cnt = cur[s] - s * cap;
    const int lo  = (int)((long long)cnt * p / P);
    const int hi  = (int)((long long)cnt * (p + 1) / P);
    const int2* __restrict__ bin = bins + (size_t)s * cap;

    auto accum = [&](int2 rec, float4 b0, float4 b1, float4 b2, float4 b3) {
        float4 v = src[rec.y & 0x1FFFF];
        float* a = acc + (((unsigned)rec.y) >> 17) * 4;
        if (PASS == 1) {
            atomicAdd(a + 0, b0.x*v.x + b1.x*v.y + b2.x*v.z + b3.x*v.w);
            atomicAdd(a + 1, b0.y*v.x + b1.y*v.y + b2.y*v.z + b3.y*v.w);
            atomicAdd(a + 2, b0.z*v.x + b1.z*v.y + b2.z*v.z + b3.z*v.w);
            atomicAdd(a + 3, b0.w*v.x + b1.w*v.y + b2.w*v.z + b3.w*v.w);
        } else {
            atomicAdd(a + 0, b0.x*v.x + b0.y*v.y + b0.z*v.z + b0.w*v.w);
            atomicAdd(a + 1, b1.x*v.x + b1.y*v.y + b1.z*v.z + b1.w*v.w);
            atomicAdd(a + 2, b2.x*v.x + b2.y*v.y + b2.z*v.z + b2.w*v.w);
            atomicAdd(a + 3, b3.x*v.x + b3.y*v.y + b3.z*v.z + b3.w*v.w);
        }
    };

    int i = lo + (int)threadIdx.x;
    for (; i + BLK < hi; i += 2 * BLK) {
        int2 ra = bin[i];
        int2 rb = bin[i + BLK];
        const float4* Ba = boo + (long long)ra.x * 4;
        const float4* Bb = boo + (long long)rb.x * 4;
        float4 a0 = Ba[0], a1 = Ba[1], a2 = Ba[2], a3 = Ba[3];
        float4 c0 = Bb[0], c1 = Bb[1], c2 = Bb[2], c3 = Bb[3];
        accum(ra, a0, a1, a2, a3);
        accum(rb, c0, c1, c2, c3);
    }
    if (i < hi) {
        int2 ra = bin[i];
        const float4* Ba = boo + (long long)ra.x * 4;
        accum(ra, Ba[0], Ba[1], Ba[2], Ba[3]);
    }
    __syncthreads();

    if (STAGED) {
        float* st = dst + (size_t)blockIdx.x * (SLICE * 4);
        for (int f = threadIdx.x; f < lim * 4; f += BLK) st[f] = acc[f];
    } else if (PASS == 1) {
        for (int f = threadIdx.x; f < lim * 4; f += BLK)
            unsafeAtomicAdd(dst + ((long long)base * 4 + f), acc[f]);
    } else {
        for (int f = threadIdx.x; f < lim * 4; f += BLK) {
            float mv = mask[base + (f >> 2)];
            unsafeAtomicAdd(dst + ((long long)base * 4 + f), acc[f] * mv);
        }
    }
}

// Staged mid: v = (sum_p stage1[s*P+p]) * diag * mask
__global__ void __launch_bounds__(BLK) mid_staged_kernel(
    const float4* __restrict__ stage,
    const float4* __restrict__ d4,
    const float*  __restrict__ mask,
    float4* __restrict__ v4,
    int N, int P)
{
    int n = blockIdx.x * BLK + threadIdx.x;
    if (n >= N) return;
    int s = n >> SLOG, local = n & (SLICE - 1);
    const float4* t = stage + ((size_t)s * P) * SLICE + local;
    float4 a = make_float4(0.f, 0.f, 0.f, 0.f);
    for (int p = 0; p < P; ++p) {
        float4 u = t[(size_t)p * SLICE];
        a.x += u.x; a.y += u.y; a.z += u.z; a.w += u.w;
    }
    float4 dv = d4[n];
    float  m  = mask[n];
    a.x *= dv.x * m; a.y *= dv.y * m; a.z *= dv.z * m; a.w *= dv.w * m;
    v4[n] = a;
}

// Staged final: out = EPSILON*x*diag + mask * (sum_p stage2[s*P+p])
__global__ void __launch_bounds__(BLK) fin_staged_kernel(
    const float4* __restrict__ stage,
    const float4* __restrict__ x4,
    const float4* __restrict__ d4,
    const float*  __restrict__ mask,
    float4* __restrict__ out4,
    int N, int P)
{
    int n = blockIdx.x * BLK + threadIdx.x;
    if (n >= N) return;
    int s = n >> SLOG, local = n & (SLICE - 1);
    const float4* t = stage + ((size_t)s * P) * SLICE + local;
    float4 a = make_float4(0.f, 0.f, 0.f, 0.f);
    for (int p = 0; p < P; ++p) {
        float4 u = t[(size_t)p * SLICE];
        a.x += u.x; a.y += u.y; a.z += u.z; a.w += u.w;
    }
    float4 xv = x4[n];
    float4 dv = d4[n];
    float  m  = mask[n];
    float4 o;
    o.x = EPSILON * xv.x * dv.x + a.x * m;
    o.y = EPSILON * xv.y * dv.y + a.y * m;
    o.z = EPSILON * xv.z * dv.z + a.z * m;
    o.w = EPSILON * xv.w * dv.w + a.w * m;
    out4[n] = o;
}

// Tier-2 mid: v = v * diag * mask (in place); out = EPSILON * x * diag
__global__ void __launch_bounds__(BLK) mid_atomic_kernel(
    const float4* __restrict__ x4,
    const float4* __restrict__ d4,
    const float*  __restrict__ mask,
    float4* __restrict__ atx,
    float4* __restrict__ out4,
    int N)
{
    int n = blockIdx.x * BLK + threadIdx.x;
    if (n >= N) return;
    float4 a  = atx[n];
    float4 dv = d4[n];
    float  m  = mask[n];
    a.x *= dv.x * m; a.y *= dv.y * m; a.z *= dv.z * m; a.w *= dv.w * m;
    atx[n] = a;
    float4 xv = x4[n];
    float4 o;
    o.x = EPSILON * xv.x * dv.x; o.y = EPSILON * xv.y * dv.y;
    o.z = EPSILON * xv.z * dv.z; o.w = EPSILON * xv.w * dv.w;
    out4[n] = o;
}

// ---- Tier-3 fallback: R0 kernels verbatim (proven 544us) -----------------
__global__ void __launch_bounds__(256) spmvt_kernel(
    const float4* __restrict__ boo, const int* __restrict__ row,
    const int* __restrict__ col, const float* __restrict__ x,
    float* __restrict__ ATx, long long E)
{
    long long t = (long long)blockIdx.x * blockDim.x + threadIdx.x;
    long long e = t >> 2;
    int j = (int)(t & 3);
    if (e >= E) return;
    float4 b = boo[e * 4 + j];
    int r = row[e];
    float xj = x[r * 4 + j];
    float4 p;
    p.x = b.x * xj; p.y = b.y * xj; p.z = b.z * xj; p.w = b.w * xj;
    p.x += __shfl_xor(p.x, 1); p.y += __shfl_xor(p.y, 1);
    p.z += __shfl_xor(p.z, 1); p.w += __shfl_xor(p.w, 1);
    p.x += __shfl_xor(p.x, 2); p.y += __shfl_xor(p.y, 2);
    p.z += __shfl_xor(p.z, 2); p.w += __shfl_xor(p.w, 2);
    float v = (j == 0) ? p.x : (j == 1) ? p.y : (j == 2) ? p.z : p.w;
    int c = col[e];
    unsafeAtomicAdd(&ATx[c * 4 + j], v);
}

__global__ void __launch_bounds__(256) spmv_kernel(
    const float4* __restrict__ boo, const int* __restrict__ row,
    const int* __restrict__ col, const float* __restrict__ vv,
    const float* __restrict__ mask, float* __restrict__ out, long long E)
{
    long long t = (long long)blockIdx.x * blockDim.x + threadIdx.x;
    long long e = t >> 2;
    int i = (int)(t & 3);
    if (e >= E) return;
    float4 b = boo[e * 4 + i];
    int c = col[e];
    const float4* v4 = (const float4*)vv;
    float4 v = v4[c];
    float mi = b.x * v.x + b.y * v.y + b.z * v.z + b.w * v.w;
    int r = row[e];
    float mr = mask[r];
    unsafeAtomicAdd(&out[r * 4 + i], mi * mr);
}

extern "C" void kernel_launch(void* const* d_in, const int* in_sizes, int n_in,
                              void* d_out, int out_size, void* d_ws, size_t ws_size,
                              hipStream_t stream) {
    const float* x    = (const float*)d_in[0];
    const int*   ei   = (const int*)d_in[1];
    const float* boo  = (const float*)d_in[2];
    const float* mask = (const float*)d_in[3];
    const float* diag = (const float*)d_in[4];
    float* out = (float*)d_out;

    int N = in_sizes[0] / 4;
    long long E = in_sizes[1] / 2;
    const int* row = ei;
    const int* col = ei + E;

    int S = (N + SLICE - 1) >> SLOG;
    int cap = (int)((E + S - 1) / S);
    cap += cap * 3 / 10;                     // 30% slack (keys fixed; 60+ sigma)
    cap = (cap + 255) & ~255;

    size_t o_v   = 0;
    size_t o_cur = ((size_t)N * 16 + 255) & ~(size_t)255;
    size_t o_b1  = o_cur + 1024;
    size_t szb   = (size_t)S * cap * 8;
    size_t o_b2  = o_b1 + szb;
    size_t o_st  = o_b2 + szb;
    size_t szst  = (size_t)S * PCH * SLICE * 16;

    bool ok   = (S <= MAXS) && (N <= (1 << 17));
    int  tier = (!ok) ? 3 : (ws_size >= o_st + szst) ? 1
                          : (ws_size >= o_st)        ? 2 : 3;

    float* v     = (float*)((char*)d_ws + o_v);
    int*   cur1  = (int*)((char*)d_ws + o_cur);
    int*   cur2  = cur1 + 128;
    int2*  bins1 = (int2*)((char*)d_ws + o_b1);
    int2*  bins2 = (int2*)((char*)d_ws + o_b2);
    float* stage = (float*)((char*)d_ws + o_st);

    const int gNode = (N + BLK - 1) / BLK;
    const int gBin  = (int)((E + BCH - 1) / BCH);
    const int gPass = S * PCH;

    if (tier <= 2) {
        init_cursors<<<1, MAXS, 0, stream>>>(cur1, cur2, S, cap);
        bin_kernel<<<gBin, BLK, 0, stream>>>(row, col, bins1, bins2, cur1, cur2, E, S);
        if (tier == 1) {
            pass_kernel<1, 1><<<gPass, BLK, 0, stream>>>(
                (const float4*)boo, bins1, cur1, (const float4*)x, mask, stage, N, cap, PCH);
            mid_staged_kernel<<<gNode, BLK, 0, stream>>>(
                (const float4*)stage, (const float4*)diag, mask, (float4*)v, N, PCH);
            pass_kernel<2, 1><<<gPass, BLK, 0, stream>>>(
                (const float4*)boo, bins2, cur2, (const float4*)v, mask, stage, N, cap, PCH);
            fin_staged_kernel<<<gNode, BLK, 0, stream>>>(
                (const float4*)stage, (const float4*)x, (const float4*)diag, mask,
                (float4*)out, N, PCH);
        } else {
            hipMemsetAsync(v, 0, (size_t)N * 16, stream);
            pass_kernel<1, 0><<<gPass, BLK, 0, stream>>>(
                (const float4*)boo, bins1, cur1, (const float4*)x, mask, v, N, cap, PCH);
            mid_atomic_kernel<<<gNode, BLK, 0, stream>>>(
                (const float4*)x, (const float4*)diag, mask, (float4*)v, (float4*)out, N);
            pass_kernel<2, 0><<<gPass, BLK, 0, stream>>>(
                (const float4*)boo, bins2, cur2, (const float4*)v, mask, out, N, cap, PCH);
        }
    } else {
        // Tier 3: R0-proven path
        hipMemsetAsync(v, 0, (size_t)N * 16, stream);
        long long T = E * 4;
        int gEdge = (int)((T + BLK - 1) / BLK);
        spmvt_kernel<<<gEdge, BLK, 0, stream>>>(
            (const float4*)boo, row, col, x, v, E);
        mid_atomic_kernel<<<gNode, BLK, 0, stream>>>(
            (const float4*)x, (const float4*)diag, mask, (float4*)v, (float4*)out, N);
        spmv_kernel<<<gEdge, BLK, 0, stream>>>(
            (const float4*)boo, row, col, v, mask, out, E);
    }
}

// Round 7
// 508.614 us; speedup vs baseline: 3.0013x; 1.0313x over previous
//
#include <hip/hip_runtime.h>

#define EPSILON 0.01f

#define BLK    256     // threads per workgroup
#define SLICE  1024    // nodes per slice -> 16 KB fp32x4 LDS accumulator
#define SLOG   10      // log2(SLICE)
#define PCH    20      // edge-pass chunks per slice (grid ~ 98*20=1960, ~8/CU)
#define BCH    4096    // edges per binning block
#define MAXS   128     // max slices supported

// ---------------------------------------------------------------------------
// R7: R6 showed the edge pass is VMEM-TRANSACTION-bound (2.3 TB/s, VALU 3%,
// ~330 uncoalesced transactions per wave-iter from per-lane 4x16B random boo
// gathers), and bin_kernel (~220us by subtraction) is store-transaction-bound
// (6.4M scattered 8B record stores). Fixes: (1) pass uses 4 lanes/record --
// lane j loads boo[rec*4+j], one contiguous 64B per record, 16 trans/wave-
// iter; PASS1 reuses R0's proven butterfly; SLICE 1024 -> 8 blocks/CU.
// (2) bin stages records in LDS ordered by slice, flushes coalesced runs
// (phase-synced radix scatter, no cross-phase counters). Tiers unchanged.
// ---------------------------------------------------------------------------

__global__ void init_cursors(int* cur1, int* cur2, int S, int cap) {
    int t = threadIdx.x;
    if (t < S) { cur1[t] = t * cap; cur2[t] = t * cap; }
}

__global__ void __launch_bounds__(BLK) bin_kernel(
    const int* __restrict__ row, const int* __restrict__ col,
    int2* __restrict__ bins1, int2* __restrict__ bins2,
    int* __restrict__ cur1, int* __restrict__ cur2,
    long long E, int S)
{
    __shared__ int2 st[BCH];              // 32 KB ordered staging
    __shared__ unsigned char ss[BCH];     // 4 KB slot -> slice
    __shared__ int hist[MAXS], rnk[MAXS], sbase[MAXS], gbase[MAXS];
    const int t = threadIdx.x;

    long long start = (long long)blockIdx.x * BCH;
    long long endl  = start + BCH; if (endl > E) endl = E;
    const int cnt = (int)(endl - start);

    for (int side = 0; side < 2; ++side) {
        const int* __restrict__ key = side ? row : col;
        const int* __restrict__ oth = side ? col : row;
        int2* __restrict__ bins = side ? bins2 : bins1;
        int*  __restrict__ cur  = side ? cur2  : cur1;

        if (t < MAXS) { hist[t] = 0; rnk[t] = 0; }
        __syncthreads();

        // phase 1: per-slice counts
        for (int i0 = t * 4; i0 < cnt; i0 += BLK * 4) {
            if (i0 + 4 <= cnt) {
                int4 k = *reinterpret_cast<const int4*>(key + start + i0);
                atomicAdd(&hist[k.x >> SLOG], 1);
                atomicAdd(&hist[k.y >> SLOG], 1);
                atomicAdd(&hist[k.z >> SLOG], 1);
                atomicAdd(&hist[k.w >> SLOG], 1);
            } else {
                for (int i = i0; i < cnt; ++i)
                    atomicAdd(&hist[key[start + i] >> SLOG], 1);
            }
        }
        __syncthreads();

        // phase 2: local exclusive scan + one global cursor add per slice
        if (t == 0) {
            int run = 0;
            for (int s2 = 0; s2 < S; ++s2) { sbase[s2] = run; run += hist[s2]; }
        }
        if (t < S) gbase[t] = atomicAdd(&cur[t], hist[t]);
        __syncthreads();

        // phase 3: scatter records into LDS, ordered by slice
        for (int i0 = t * 4; i0 < cnt; i0 += BLK * 4) {
            if (i0 + 4 <= cnt) {
                int4 k = *reinterpret_cast<const int4*>(key + start + i0);
                int4 o = *reinterpret_cast<const int4*>(oth + start + i0);
                int kk[4] = {k.x, k.y, k.z, k.w};
                int oo[4] = {o.x, o.y, o.z, o.w};
                #pragma unroll
                for (int u = 0; u < 4; ++u) {
                    int s2 = kk[u] >> SLOG;
                    int slot = sbase[s2] + atomicAdd(&rnk[s2], 1);
                    st[slot] = make_int2((int)(start + i0 + u),
                                         ((kk[u] & (SLICE - 1)) << 17) | oo[u]);
                    ss[slot] = (unsigned char)s2;
                }
            } else {
                for (int i = i0; i < cnt; ++i) {
                    int kv = key[start + i], ov = oth[start + i];
                    int s2 = kv >> SLOG;
                    int slot = sbase[s2] + atomicAdd(&rnk[s2], 1);
                    st[slot] = make_int2((int)(start + i),
                                         ((kv & (SLICE - 1)) << 17) | ov);
                    ss[slot] = (unsigned char)s2;
                }
            }
        }
        __syncthreads();

        // phase 4: coalesced flush (consecutive slots -> consecutive dst)
        for (int i = t; i < cnt; i += BLK) {
            int s2 = ss[i];
            bins[(size_t)gbase[s2] + (i - sbase[s2])] = st[i];
        }
        __syncthreads();
    }
}

// Dense sliced edge pass, 4 lanes per record (coalesced 64B boo reads).
// PASS1: msg_t[i]=sum_j B[j][i]*x[src] (R0 butterfly); PASS2: lane j computes
// msg[j]=dot(B[j][:],v[src]) directly.
template<int PASS, int STAGED>
__global__ void __launch_bounds__(BLK) pass_kernel(
    const float4* __restrict__ boo,
    const int2*   __restrict__ bins,
    const int*    __restrict__ cur,    // post-bin cursors (start + count)
    const float4* __restrict__ src,
    const float*  __restrict__ mask,
    float*        __restrict__ dst,    // STAGED: stage base; else ATx/out
    int N, int cap, int P)
{
    __shared__ float acc[SLICE * 4];   // 16 KB

    const int s    = blockIdx.x / P;
    const int p    = blockIdx.x - s * P;
    const int base = s << SLOG;
    const int lim  = min(SLICE, N - base);

    for (int i = threadIdx.x; i < SLICE * 4; i += BLK) acc[i] = 0.0f;
    __syncthreads();

    const int cnt = cur[s] - s * cap;
    const int lo  = (int)((long long)cnt * p / P);
    const int hi  = (int)((long long)cnt * (p + 1) / P);
    const int2* __restrict__ bin = bins + (size_t)s * cap;

    const int j  = (int)(threadIdx.x & 3);
    const int g0 = (int)(threadIdx.x >> 2);      // 64 groups per block

    auto process = [&](int2 rec, float4 b) {
        float4 v = src[rec.y & 0x1FFFF];
        int loc = ((unsigned)rec.y) >> 17;
        float val;
        if (PASS == 2) {
            val = b.x * v.x + b.y * v.y + b.z * v.z + b.w * v.w;
        } else {
            float xj = (j == 0) ? v.x : (j == 1) ? v.y : (j == 2) ? v.z : v.w;
            float4 q;
            q.x = b.x * xj; q.y = b.y * xj; q.z = b.z * xj; q.w = b.w * xj;
            q.x += __shfl_xor(q.x, 1); q.y += __shfl_xor(q.y, 1);
            q.z += __shfl_xor(q.z, 1); q.w += __shfl_xor(q.w, 1);
            q.x += __shfl_xor(q.x, 2); q.y += __shfl_xor(q.y, 2);
            q.z += __shfl_xor(q.z, 2); q.w += __shfl_xor(q.w, 2);
            val = (j == 0) ? q.x : (j == 1) ? q.y : (j == 2) ? q.z : q.w;
        }
        atomicAdd(&acc[loc * 4 + j], val);
    };

    int i = lo + g0;
    for (; i + 64 < hi; i += 128) {              // 2-way unroll for MLP
        int2 ra = bin[i];
        int2 rb = bin[i + 64];
        float4 ba = boo[(long long)ra.x * 4 + j];
        float4 bb = boo[(long long)rb.x * 4 + j];
        process(ra, ba);
        process(rb, bb);
    }
    if (i < hi) {
        int2 ra = bin[i];
        float4 ba = boo[(long long)ra.x * 4 + j];
        process(ra, ba);
    }
    __syncthreads();

    if (STAGED) {
        float* stg = dst + (size_t)blockIdx.x * (SLICE * 4);
        for (int f = threadIdx.x; f < lim * 4; f += BLK) stg[f] = acc[f];
    } else if (PASS == 1) {
        for (int f = threadIdx.x; f < lim * 4; f += BLK)
            unsafeAtomicAdd(dst + ((long long)base * 4 + f), acc[f]);
    } else {
        for (int f = threadIdx.x; f < lim * 4; f += BLK) {
            float mv = mask[base + (f >> 2)];
            unsafeAtomicAdd(dst + ((long long)base * 4 + f), acc[f] * mv);
        }
    }
}

// Staged mid: v = (sum_p stage1[s*P+p]) * diag * mask
__global__ void __launch_bounds__(BLK) mid_staged_kernel(
    const float4* __restrict__ stage,
    const float4* __restrict__ d4,
    const float*  __restrict__ mask,
    float4* __restrict__ v4,
    int N, int P)
{
    int n = blockIdx.x * BLK + threadIdx.x;
    if (n >= N) return;
    int s = n >> SLOG, local = n & (SLICE - 1);
    const float4* t = stage + ((size_t)s * P) * SLICE + local;
    float4 a = make_float4(0.f, 0.f, 0.f, 0.f);
    for (int p = 0; p < P; ++p) {
        float4 u = t[(size_t)p * SLICE];
        a.x += u.x; a.y += u.y; a.z += u.z; a.w += u.w;
    }
    float4 dv = d4[n];
    float  m  = mask[n];
    a.x *= dv.x * m; a.y *= dv.y * m; a.z *= dv.z * m; a.w *= dv.w * m;
    v4[n] = a;
}

// Staged final: out = EPSILON*x*diag + mask * (sum_p stage2[s*P+p])
__global__ void __launch_bounds__(BLK) fin_staged_kernel(
    const float4* __restrict__ stage,
    const float4* __restrict__ x4,
    const float4* __restrict__ d4,
    const float*  __restrict__ mask,
    float4* __restrict__ out4,
    int N, int P)
{
    int n = blockIdx.x * BLK + threadIdx.x;
    if (n >= N) return;
    int s = n >> SLOG, local = n & (SLICE - 1);
    const float4* t = stage + ((size_t)s * P) * SLICE + local;
    float4 a = make_float4(0.f, 0.f, 0.f, 0.f);
    for (int p = 0; p < P; ++p) {
        float4 u = t[(size_t)p * SLICE];
        a.x += u.x; a.y += u.y; a.z += u.z; a.w += u.w;
    }
    float4 xv = x4[n];
    float4 dv = d4[n];
    float  m  = mask[n];
    float4 o;
    o.x = EPSILON * xv.x * dv.x + a.x * m;
    o.y = EPSILON * xv.y * dv.y + a.y * m;
    o.z = EPSILON * xv.z * dv.z + a.z * m;
    o.w = EPSILON * xv.w * dv.w + a.w * m;
    out4[n] = o;
}

// Tier-2 mid: v = v * diag * mask (in place); out = EPSILON * x * diag
__global__ void __launch_bounds__(BLK) mid_atomic_kernel(
    const float4* __restrict__ x4,
    const float4* __restrict__ d4,
    const float*  __restrict__ mask,
    float4* __restrict__ atx,
    float4* __restrict__ out4,
    int N)
{
    int n = blockIdx.x * BLK + threadIdx.x;
    if (n >= N) return;
    float4 a  = atx[n];
    float4 dv = d4[n];
    float  m  = mask[n];
    a.x *= dv.x * m; a.y *= dv.y * m; a.z *= dv.z * m; a.w *= dv.w * m;
    atx[n] = a;
    float4 xv = x4[n];
    float4 o;
    o.x = EPSILON * xv.x * dv.x; o.y = EPSILON * xv.y * dv.y;
    o.z = EPSILON * xv.z * dv.z; o.w = EPSILON * xv.w * dv.w;
    out4[n] = o;
}

// ---- Tier-3 fallback: R0 kernels verbatim (proven 544us) -----------------
__global__ void __launch_bounds__(256) spmvt_kernel(
    const float4* __restrict__ boo, const int* __restrict__ row,
    const int* __restrict__ col, const float* __restrict__ x,
    float* __restrict__ ATx, long long E)
{
    long long t = (long long)blockIdx.x * blockDim.x + threadIdx.x;
    long long e = t >> 2;
    int j = (int)(t & 3);
    if (e >= E) return;
    float4 b = boo[e * 4 + j];
    int r = row[e];
    float xj = x[r * 4 + j];
    float4 p;
    p.x = b.x * xj; p.y = b.y * xj; p.z = b.z * xj; p.w = b.w * xj;
    p.x += __shfl_xor(p.x, 1); p.y += __shfl_xor(p.y, 1);
    p.z += __shfl_xor(p.z, 1); p.w += __shfl_xor(p.w, 1);
    p.x += __shfl_xor(p.x, 2); p.y += __shfl_xor(p.y, 2);
    p.z += __shfl_xor(p.z, 2); p.w += __shfl_xor(p.w, 2);
    float v = (j == 0) ? p.x : (j == 1) ? p.y : (j == 2) ? p.z : p.w;
    int c = col[e];
    unsafeAtomicAdd(&ATx[c * 4 + j], v);
}

__global__ void __launch_bounds__(256) spmv_kernel(
    const float4* __restrict__ boo, const int* __restrict__ row,
    const int* __restrict__ col, const float* __restrict__ vv,
    const float* __restrict__ mask, float* __restrict__ out, long long E)
{
    long long t = (long long)blockIdx.x * blockDim.x + threadIdx.x;
    long long e = t >> 2;
    int i = (int)(t & 3);
    if (e >= E) return;
    float4 b = boo[e * 4 + i];
    int c = col[e];
    const float4* v4 = (const float4*)vv;
    float4 v = v4[c];
    float mi = b.x * v.x + b.y * v.y + b.z * v.z + b.w * v.w;
    int r = row[e];
    float mr = mask[r];
    unsafeAtomicAdd(&out[r * 4 + i], mi * mr);
}

extern "C" void kernel_launch(void* const* d_in, const int* in_sizes, int n_in,
                              void* d_out, int out_size, void* d_ws, size_t ws_size,
                              hipStream_t stream) {
    const float* x    = (const float*)d_in[0];
    const int*   ei   = (const int*)d_in[1];
    const float* boo  = (const float*)d_in[2];
    const float* mask = (const float*)d_in[3];
    const float* diag = (const float*)d_in[4];
    float* out = (float*)d_out;

    int N = in_sizes[0] / 4;
    long long E = in_sizes[1] / 2;
    const int* row = ei;
    const int* col = ei + E;

    int S = (N + SLICE - 1) >> SLOG;
    int cap = (int)((E + S - 1) / S);
    cap += cap * 3 / 10;                     // 30% slack (keys fixed; 60+ sigma)
    cap = (cap + 255) & ~255;

    size_t o_v   = 0;
    size_t o_cur = ((size_t)N * 16 + 255) & ~(size_t)255;
    size_t o_b1  = o_cur + 2048;
    size_t szb   = (size_t)S * cap * 8;
    size_t o_b2  = o_b1 + szb;
    size_t o_st  = o_b2 + szb;
    size_t szst  = (size_t)S * PCH * SLICE * 16;

    bool ok   = (S <= MAXS) && (N <= (1 << 17));
    int  tier = (!ok) ? 3 : (ws_size >= o_st + szst) ? 1
                          : (ws_size >= o_st)        ? 2 : 3;

    float* v     = (float*)((char*)d_ws + o_v);
    int*   cur1  = (int*)((char*)d_ws + o_cur);
    int*   cur2  = cur1 + 256;
    int2*  bins1 = (int2*)((char*)d_ws + o_b1);
    int2*  bins2 = (int2*)((char*)d_ws + o_b2);
    float* stage = (float*)((char*)d_ws + o_st);

    const int gNode = (N + BLK - 1) / BLK;
    const int gBin  = (int)((E + BCH - 1) / BCH);
    const int gPass = S * PCH;

    if (tier <= 2) {
        init_cursors<<<1, MAXS, 0, stream>>>(cur1, cur2, S, cap);
        bin_kernel<<<gBin, BLK, 0, stream>>>(row, col, bins1, bins2, cur1, cur2, E, S);
        if (tier == 1) {
            pass_kernel<1, 1><<<gPass, BLK, 0, stream>>>(
                (const float4*)boo, bins1, cur1, (const float4*)x, mask, stage, N, cap, PCH);
            mid_staged_kernel<<<gNode, BLK, 0, stream>>>(
                (const float4*)stage, (const float4*)diag, mask, (float4*)v, N, PCH);
            pass_kernel<2, 1><<<gPass, BLK, 0, stream>>>(
                (const float4*)boo, bins2, cur2, (const float4*)v, mask, stage, N, cap, PCH);
            fin_staged_kernel<<<gNode, BLK, 0, stream>>>(
                (const float4*)stage, (const float4*)x, (const float4*)diag, mask,
                (float4*)out, N, PCH);
        } else {
            hipMemsetAsync(v, 0, (size_t)N * 16, stream);
            pass_kernel<1, 0><<<gPass, BLK, 0, stream>>>(
                (const float4*)boo, bins1, cur1, (const float4*)x, mask, v, N, cap, PCH);
            mid_atomic_kernel<<<gNode, BLK, 0, stream>>>(
                (const float4*)x, (const float4*)diag, mask, (float4*)v, (float4*)out, N);
            pass_kernel<2, 0><<<gPass, BLK, 0, stream>>>(
                (const float4*)boo, bins2, cur2, (const float4*)v, mask, out, N, cap, PCH);
        }
    } else {
        // Tier 3: R0-proven path
        hipMemsetAsync(v, 0, (size_t)N * 16, stream);
        long long T = E * 4;
        int gEdge = (int)((T + BLK - 1) / BLK);
        spmvt_kernel<<<gEdge, BLK, 0, stream>>>(
            (const float4*)boo, row, col, x, v, E);
        mid_atomic_kernel<<<gNode, BLK, 0, stream>>>(
            (const float4*)x, (const float4*)diag, mask, (float4*)v, (float4*)out, N);
        spmv_kernel<<<gEdge, BLK, 0, stream>>>(
            (const float4*)boo, row, col, v, mask, out, E);
    }
}